// Round 4
// baseline (2620.391 us; speedup 1.0000x reference)
//
#include <hip/hip_runtime.h>

#define MM 200000      // messages
#define AA 100000      // atoms
#define KA 6
#define KB 5
#define NATOM 120
#define NBOND 4
#define NC (NATOM*NBOND)   // 480 combos
#define HH 256
#define HU_LD 512          // interleaved row: [0..255]=h, [256..511]=uh

typedef unsigned short ushort_t;
typedef __attribute__((ext_vector_type(8))) short bf16x8;
typedef __attribute__((ext_vector_type(4))) float f32x4;
typedef __attribute__((ext_vector_type(4))) unsigned int u32x4;
typedef __attribute__((ext_vector_type(2))) unsigned int u32x2;

// canonical bf16 weight arena offsets (ushort elements)
#define OFF_Ea   0
#define OFF_Eb   30720
#define OFF_Wz   31744
#define OFF_Wzb  228352
#define OFF_Wr   228608
#define OFF_Ur   359680
#define OFF_Urb  425216
#define OFF_Wh   425472
#define OFF_Whb  622080
#define OFF_O1   622336
#define OFF_O1b  753408
#define OFF_O2   753664
#define OFF_O2b  819200
#define W_TOTAL  819456

// ---------------- static device state ----------------
__device__ ushort_t g_hu0[MM*HU_LD];  // ping
__device__ ushort_t g_hu1[MM*HU_LD];  // pong
__device__ float    g_tr[NC*HH];      // x@Wr^T + Ur_b   per combo
__device__ float    g_tz[NC*HH];      // x-part of z preact + Wz_b
__device__ float    g_th[NC*HH];      // x-part of h preact + Wh_b
__device__ float    g_to1[NATOM*HH];  // hnode-part of O1 preact + O1_b
__device__ int      g_cidx[MM];
__device__ ushort_t c_w[W_TOTAL];     // canonical bf16 weights
__device__ int      g_isf32;          // 1 if float inputs are f32

// ---------------- helpers ----------------
__device__ inline float bf2f(ushort_t u){ return __uint_as_float(((unsigned)u)<<16); }
__device__ inline ushort_t f2bf(float f){
  unsigned u = __float_as_uint(f);
  unsigned r = (u + 0x7FFFu + ((u>>16)&1u)) >> 16;
  return (ushort_t)r;
}
__device__ inline float sigm(float x){ return 1.0f/(1.0f + __expf(-x)); }
__device__ inline float tanh_f(float x){
  float ax = fabsf(x);
  float e = __expf(-2.0f*ax);
  float t = (1.0f - e)/(1.0f + e);
  return copysignf(t, x);
}
// LDS swizzle: ushort-index within a [rows][256] bf16 tile (XOR bits 3..5 by row&7)
__device__ inline int sidx(int row, int col){ return row*256 + (col ^ ((row&7)<<3)); }

__device__ inline bf16x8 ldsA(const ushort_t* tile, int m0, int lane, int k0){
  int row = m0 + (lane & 15);
  int col = k0 + 8*(lane>>4);
  return *(const bf16x8*)(tile + sidx(row, col));
}
__device__ inline bf16x8 ldgB(const ushort_t* W, int ldw, int koff, int n0, int lane, int k0){
  int n = n0 + (lane & 15);
  int k = koff + k0 + 8*(lane>>4);
  return *(const bf16x8*)(W + n*ldw + k);
}
__device__ inline f32x4 mfma16(bf16x8 a, bf16x8 b, f32x4 c){
  return __builtin_amdgcn_mfma_f32_16x16x32_bf16(a, b, c, 0, 0, 0);
}
__device__ inline void nt_store16(ushort_t* p, const ushort_t* lds_src){
  u32x4 v = *(const u32x4*)lds_src;
  __builtin_nontemporal_store(v, (u32x4*)p);
}

// ---------------- K-detect: is the float data f32 or bf16? ------------------
__global__ __launch_bounds__(256) void k_detect(const ushort_t* Ea_raw){
  __shared__ int sbad;
  if (threadIdx.x == 0) sbad = 0;
  __syncthreads();
  float v = bf2f(Ea_raw[2*threadIdx.x]);
  float av = fabsf(v);
  int bad = (av > 1e4f) || (av != 0.0f && av < 1e-30f);
  atomicAdd(&sbad, bad);
  __syncthreads();
  if (threadIdx.x == 0) g_isf32 = (sbad > 64) ? 1 : 0;
}

// ---------------- K-convert: build canonical bf16 arena ---------------------
__global__ __launch_bounds__(256) void k_convert(
    const void* Ea, const void* Eb, const void* Wz, const void* Wzb,
    const void* Wr, const void* Ur, const void* Urb, const void* Wh,
    const void* Whb, const void* O1, const void* O1b, const void* O2,
    const void* O2b)
{
  int idx = blockIdx.x*256 + threadIdx.x;
  if (idx >= W_TOTAL) return;
  const void* src; int j;
  if      (idx < OFF_Eb)  { src = Ea;  j = idx - OFF_Ea; }
  else if (idx < OFF_Wz)  { src = Eb;  j = idx - OFF_Eb; }
  else if (idx < OFF_Wzb) { src = Wz;  j = idx - OFF_Wz; }
  else if (idx < OFF_Wr)  { src = Wzb; j = idx - OFF_Wzb; }
  else if (idx < OFF_Ur)  { src = Wr;  j = idx - OFF_Wr; }
  else if (idx < OFF_Urb) { src = Ur;  j = idx - OFF_Ur; }
  else if (idx < OFF_Wh)  { src = Urb; j = idx - OFF_Urb; }
  else if (idx < OFF_Whb) { src = Wh;  j = idx - OFF_Wh; }
  else if (idx < OFF_O1)  { src = Whb; j = idx - OFF_Whb; }
  else if (idx < OFF_O1b) { src = O1;  j = idx - OFF_O1; }
  else if (idx < OFF_O2)  { src = O1b; j = idx - OFF_O1b; }
  else if (idx < OFF_O2b) { src = O2;  j = idx - OFF_O2; }
  else                    { src = O2b; j = idx - OFF_O2b; }
  ushort_t v;
  if (g_isf32) v = f2bf(((const float*)src)[j]);
  else         v = ((const ushort_t*)src)[j];
  c_w[idx] = v;
}

// ---------------- K0: build tables -----------------------------------------
__global__ __launch_bounds__(256) void k_tables()
{
  const ushort_t* Ea  = c_w + OFF_Ea;
  const ushort_t* Eb  = c_w + OFF_Eb;
  int b = blockIdx.x, o = threadIdx.x;
  if (b < 3*NC) {
    int t = b / NC, c = b % NC, a = c >> 2, bd = c & 3;
    const ushort_t* W; const ushort_t* bias; int ldw;
    if (t == 0)      { W = c_w + OFF_Wr; bias = c_w + OFF_Urb; ldw = 512; }
    else if (t == 1) { W = c_w + OFF_Wz; bias = c_w + OFF_Wzb; ldw = 768; }
    else             { W = c_w + OFF_Wh; bias = c_w + OFF_Whb; ldw = 768; }
    float acc = bf2f(bias[o]);
    const ushort_t* wrow = W + o*ldw;
    for (int d = 0; d < 256; d++) acc += bf2f(Ea[a*256+d]) * bf2f(wrow[d]);
    for (int d = 0; d < 256; d++) acc += bf2f(Eb[bd*256+d]) * bf2f(wrow[256+d]);
    float* T = (t==0) ? g_tr : (t==1) ? g_tz : g_th;
    T[c*256 + o] = acc;
  } else {
    int a = b - 3*NC;
    float acc = bf2f(c_w[OFF_O1b + o]);
    const ushort_t* wrow = c_w + OFF_O1 + o*512;
    for (int d = 0; d < 256; d++) acc += bf2f(Ea[a*256+d]) * bf2f(wrow[d]);
    g_to1[a*256 + o] = acc;
  }
}

// ---------------- K1: combo index per message ------------------------------
__global__ __launch_bounds__(256) void k_cidx(const int* fnode, const int* fsrc, const int* fbond){
  int m = blockIdx.x*256 + threadIdx.x;
  if (m >= MM) return;
  g_cidx[m] = fnode[fsrc[m]]*4 + fbond[m];
}

// ---------------- K2: iteration 0 (h=0 -> table only) + Uh GEMM ------------
__global__ __launch_bounds__(256) void k_iter0(){
  __shared__ __align__(16) ushort_t sT[64*256];
  const ushort_t* Ur = c_w + OFF_Ur;
  ushort_t* hu = g_hu0;
  int base = blockIdx.x * 64;
  int t = threadIdx.x;
  {
    int row = t >> 2, cb = (t & 3) * 64;
    int m = base + row;
    int c = g_cidx[m];
    float msk = (m != 0) ? 1.0f : 0.0f;
    #pragma unroll
    for (int e = 0; e < 64; e += 4){
      int col = cb + e;
      float4 tz = *(const float4*)(g_tz + c*256 + col);
      float4 th = *(const float4*)(g_th + c*256 + col);
      ushort_t h0 = f2bf(msk * sigm(tz.x) * tanh_f(th.x));
      ushort_t h1 = f2bf(msk * sigm(tz.y) * tanh_f(th.y));
      ushort_t h2 = f2bf(msk * sigm(tz.z) * tanh_f(th.z));
      ushort_t h3 = f2bf(msk * sigm(tz.w) * tanh_f(th.w));
      u32x2 hp = (u32x2){(unsigned)h0 | ((unsigned)h1<<16), (unsigned)h2 | ((unsigned)h3<<16)};
      __builtin_nontemporal_store(hp, (u32x2*)(hu + (size_t)m*HU_LD + col));
      *(ushort4*)(sT + sidx(row, col)) = make_ushort4(h0,h1,h2,h3);
    }
  }
  __syncthreads();
  int w = t >> 6, lane = t & 63, n0w = w*64, ln = lane & 15, hi = lane >> 4;
  f32x4 acc[4][4];
  #pragma unroll
  for (int i=0;i<4;i++)
    #pragma unroll
    for (int j=0;j<4;j++) acc[i][j] = (f32x4){0.f,0.f,0.f,0.f};
  for (int kt = 0; kt < 8; kt++){
    int k0 = kt*32;
    bf16x8 aF[4], bF[4];
    #pragma unroll
    for (int i=0;i<4;i++) aF[i] = ldsA(sT, i*16, lane, k0);
    #pragma unroll
    for (int i=0;i<4;i++) bF[i] = ldgB(Ur, 256, 0, n0w + i*16, lane, k0);
    #pragma unroll
    for (int mi=0;mi<4;mi++)
      #pragma unroll
      for (int ni=0;ni<4;ni++) acc[mi][ni] = mfma16(aF[mi], bF[ni], acc[mi][ni]);
  }
  __syncthreads();  // done reading sT; reuse for uh staging
  #pragma unroll
  for (int mi=0;mi<4;mi++)
    #pragma unroll
    for (int ni=0;ni<4;ni++){
      int col = n0w + ni*16 + ln;
      #pragma unroll
      for (int r=0;r<4;r++){
        int rowl = mi*16 + hi*4 + r;
        sT[sidx(rowl, col)] = f2bf(acc[mi][ni][r]);
      }
    }
  __syncthreads();
  {
    int row = t >> 2, c0 = (t & 3) * 64;
    size_t rb = (size_t)(base+row)*HU_LD + 256;
    #pragma unroll
    for (int e = 0; e < 8; e++){
      int col = c0 + e*8;
      nt_store16(hu + rb + col, sT + sidx(row, col));
    }
  }
}

// ---------------- K-fused: gather + GRU update + Uh GEMM (ping-pong) -------
__global__ __launch_bounds__(256) void k_fused(const int* __restrict__ bgraph, int rd, int last){
  __shared__ __align__(16) ushort_t sA[32*256];  // sum_h -> uh_new staging
  __shared__ __align__(16) ushort_t sB[32*256];  // sum_gated -> h_new
  __shared__ int sC[32];
  const ushort_t* __restrict__ hup = rd ? g_hu1 : g_hu0;
  ushort_t* hun = rd ? g_hu0 : g_hu1;
  const ushort_t* Wz = c_w + OFF_Wz;
  const ushort_t* Wh = c_w + OFF_Wh;
  const ushort_t* Ur = c_w + OFF_Ur;
  int base = blockIdx.x*32, t = threadIdx.x;
  int w = t>>6, lane = t&63;

  // ---- gather phase: 8 rows per wave, each lane covers 4 cols ----
  #pragma unroll
  for (int i = 0; i < 8; i++){
    int row = w*8 + i;
    int m = base + row;
    int c = g_cidx[m];
    if (lane == 0) sC[row] = c;
    float4 tr = *(const float4*)(g_tr + c*256 + lane*4);
    int js[KB];
    #pragma unroll
    for (int k = 0; k < KB; k++) js[k] = bgraph[m*KB + k];
    // issue all 10 row loads before consuming (max outstanding loads)
    ushort4 hvv[KB], uvv[KB];
    #pragma unroll
    for (int k = 0; k < KB; k++){
      const ushort_t* rp = hup + (size_t)js[k]*HU_LD;
      hvv[k] = *(const ushort4*)(rp + lane*4);
      uvv[k] = *(const ushort4*)(rp + 256 + lane*4);
    }
    float sh0=0,sh1=0,sh2=0,sh3=0, sg0=0,sg1=0,sg2=0,sg3=0;
    #pragma unroll
    for (int k = 0; k < KB; k++){
      float h0=bf2f(hvv[k].x), h1=bf2f(hvv[k].y), h2=bf2f(hvv[k].z), h3=bf2f(hvv[k].w);
      float r0=sigm(tr.x+bf2f(uvv[k].x)), r1=sigm(tr.y+bf2f(uvv[k].y));
      float r2=sigm(tr.z+bf2f(uvv[k].z)), r3=sigm(tr.w+bf2f(uvv[k].w));
      sh0+=h0; sh1+=h1; sh2+=h2; sh3+=h3;
      sg0+=r0*h0; sg1+=r1*h1; sg2+=r2*h2; sg3+=r3*h3;
    }
    *(ushort4*)(sA + sidx(row, lane*4)) = make_ushort4(f2bf(sh0),f2bf(sh1),f2bf(sh2),f2bf(sh3));
    *(ushort4*)(sB + sidx(row, lane*4)) = make_ushort4(f2bf(sg0),f2bf(sg1),f2bf(sg2),f2bf(sg3));
  }
  __syncthreads();

  // ---- GEMM phase: z (sA x Wz) and pre_h (sB x Wh) ----
  int n0w = w*64, ln = lane&15, hi = lane>>4;
  f32x4 accz[2][4], acch[2][4];
  #pragma unroll
  for (int i=0;i<2;i++)
    #pragma unroll
    for (int j=0;j<4;j++){ accz[i][j]=(f32x4){0,0,0,0}; acch[i][j]=(f32x4){0,0,0,0}; }
  for (int kt = 0; kt < 8; kt++){
    int k0 = kt*32;
    bf16x8 aF[2], bF[4];
    aF[0] = ldsA(sA, 0, lane, k0);
    aF[1] = ldsA(sA, 16, lane, k0);
    #pragma unroll
    for (int i=0;i<4;i++) bF[i] = ldgB(Wz, 768, 512, n0w + i*16, lane, k0);
    #pragma unroll
    for (int mi=0;mi<2;mi++)
      #pragma unroll
      for (int ni=0;ni<4;ni++) accz[mi][ni] = mfma16(aF[mi], bF[ni], accz[mi][ni]);
  }
  for (int kt = 0; kt < 8; kt++){
    int k0 = kt*32;
    bf16x8 aF[2], bF[4];
    aF[0] = ldsA(sB, 0, lane, k0);
    aF[1] = ldsA(sB, 16, lane, k0);
    #pragma unroll
    for (int i=0;i<4;i++) bF[i] = ldgB(Wh, 768, 512, n0w + i*16, lane, k0);
    #pragma unroll
    for (int mi=0;mi<2;mi++)
      #pragma unroll
      for (int ni=0;ni<4;ni++) acch[mi][ni] = mfma16(aF[mi], bF[ni], acch[mi][ni]);
  }
  __syncthreads();   // all waves done reading sA/sB

  // ---- epilogue: GRU update into sB (LDS only; global writes deferred) ----
  #pragma unroll
  for (int mi=0;mi<2;mi++)
    #pragma unroll
    for (int ni=0;ni<4;ni++){
      int col = n0w + ni*16 + ln;
      #pragma unroll
      for (int r=0;r<4;r++){
        int rowl = mi*16 + hi*4 + r;
        int rowg = base + rowl;
        int c = sC[rowl];
        float shv = bf2f(sA[sidx(rowl, col)]);
        float z  = sigm(g_tz[c*256+col] + accz[mi][ni][r]);
        float ph = tanh_f(g_th[c*256+col] + acch[mi][ni][r]);
        float hn = (1.0f - z)*shv + z*ph;
        if (rowg == 0) hn = 0.f;
        sB[sidx(rowl,col)] = f2bf(hn);
      }
    }
  __syncthreads();   // sB = h_new visible; sA free

  if (!last){
    // ---- Uh GEMM: h_new x Ur^T, stage into sA ----
    f32x4 accu[2][4];
    #pragma unroll
    for (int i=0;i<2;i++)
      #pragma unroll
      for (int j=0;j<4;j++) accu[i][j]=(f32x4){0,0,0,0};
    for (int kt = 0; kt < 8; kt++){
      int k0 = kt*32;
      bf16x8 aF[2], bF[4];
      aF[0] = ldsA(sB, 0, lane, k0);
      aF[1] = ldsA(sB, 16, lane, k0);
      #pragma unroll
      for (int i=0;i<4;i++) bF[i] = ldgB(Ur, 256, 0, n0w + i*16, lane, k0);
      #pragma unroll
      for (int mi=0;mi<2;mi++)
        #pragma unroll
        for (int ni=0;ni<4;ni++) accu[mi][ni] = mfma16(aF[mi], bF[ni], accu[mi][ni]);
    }
    #pragma unroll
    for (int mi=0;mi<2;mi++)
      #pragma unroll
      for (int ni=0;ni<4;ni++){
        int col = n0w + ni*16 + ln;
        #pragma unroll
        for (int r=0;r<4;r++){
          int rowl = mi*16 + hi*4 + r;
          sA[sidx(rowl, col)] = f2bf(accu[mi][ni][r]);
        }
      }
    __syncthreads();
  }

  // ---- vectorized NT write phase: h (sB) always, uh (sA) if !last ----
  {
    int row = t>>3, c0 = (t&7)*32;
    size_t rb = (size_t)(base+row)*HU_LD;
    #pragma unroll
    for (int e = 0; e < 4; e++){
      int col = c0 + e*8;
      nt_store16(hun + rb + col, sB + sidx(row, col));
    }
    if (!last){
      #pragma unroll
      for (int e = 0; e < 4; e++){
        int col = c0 + e*8;
        nt_store16(hun + rb + 256 + col, sA + sidx(row, col));
      }
    }
  }
}

// ---------------- K5: tail (agraph gather + O1 relu + O2) ------------------
__global__ __launch_bounds__(256) void k_tail(const int* agraph, const int* fnode,
                                              void* out_v, int rd){
  __shared__ __align__(16) ushort_t sT[64*256];
  const ushort_t* __restrict__ hup = rd ? g_hu1 : g_hu0;
  const ushort_t* O1  = c_w + OFF_O1;
  const ushort_t* O2  = c_w + OFF_O2;
  const ushort_t* O2b = c_w + OFF_O2b;
  int base = blockIdx.x*64, t = threadIdx.x;
  int w = t>>6, lane = t&63;
  for (int i = 0; i < 16; i++){
    int rowl = w*16 + i;
    int a = base + rowl;
    float a0=0,a1=0,a2=0,a3=0;
    if (a < AA){
      int js[KA];
      #pragma unroll
      for (int k = 0; k < KA; k++) js[k] = agraph[a*KA + k];
      ushort4 hvv[KA];
      #pragma unroll
      for (int k = 0; k < KA; k++)
        hvv[k] = *(const ushort4*)(hup + (size_t)js[k]*HU_LD + lane*4);
      #pragma unroll
      for (int k = 0; k < KA; k++){
        a0+=bf2f(hvv[k].x); a1+=bf2f(hvv[k].y); a2+=bf2f(hvv[k].z); a3+=bf2f(hvv[k].w);
      }
    }
    *(ushort4*)(sT + sidx(rowl, lane*4)) = make_ushort4(f2bf(a0),f2bf(a1),f2bf(a2),f2bf(a3));
  }
  __syncthreads();
  int n0w = w*64, ln = lane&15, hi = lane>>4;
  f32x4 acc[4][4];
  #pragma unroll
  for (int i=0;i<4;i++)
    #pragma unroll
    for (int j=0;j<4;j++) acc[i][j]=(f32x4){0,0,0,0};
  for (int kt = 0; kt < 8; kt++){
    int k0 = kt*32;
    bf16x8 aF[4], bF[4];
    #pragma unroll
    for (int i=0;i<4;i++) aF[i] = ldsA(sT, i*16, lane, k0);
    #pragma unroll
    for (int i=0;i<4;i++) bF[i] = ldgB(O1, 512, 256, n0w + i*16, lane, k0);
    #pragma unroll
    for (int mi=0;mi<4;mi++)
      #pragma unroll
      for (int ni=0;ni<4;ni++) acc[mi][ni] = mfma16(aF[mi], bF[ni], acc[mi][ni]);
  }
  __syncthreads();
  #pragma unroll
  for (int mi=0;mi<4;mi++)
    #pragma unroll
    for (int ni=0;ni<4;ni++){
      int col = n0w + ni*16 + ln;
      #pragma unroll
      for (int r=0;r<4;r++){
        int rowl = mi*16 + hi*4 + r;
        int a = base + rowl;
        int tt = (a < AA) ? fnode[a] : 0;
        float pre = g_to1[tt*256+col] + acc[mi][ni][r];
        sT[sidx(rowl,col)] = f2bf(fmaxf(pre, 0.f));
      }
    }
  __syncthreads();
  f32x4 acco[4][4];
  #pragma unroll
  for (int i=0;i<4;i++)
    #pragma unroll
    for (int j=0;j<4;j++) acco[i][j]=(f32x4){0,0,0,0};
  for (int kt = 0; kt < 8; kt++){
    int k0 = kt*32;
    bf16x8 aF[4], bF[4];
    #pragma unroll
    for (int i=0;i<4;i++) aF[i] = ldsA(sT, i*16, lane, k0);
    #pragma unroll
    for (int i=0;i<4;i++) bF[i] = ldgB(O2, 256, 0, n0w + i*16, lane, k0);
    #pragma unroll
    for (int mi=0;mi<4;mi++)
      #pragma unroll
      for (int ni=0;ni<4;ni++) acco[mi][ni] = mfma16(aF[mi], bF[ni], acco[mi][ni]);
  }
  int isf32 = g_isf32;
  #pragma unroll
  for (int mi=0;mi<4;mi++)
    #pragma unroll
    for (int ni=0;ni<4;ni++){
      int col = n0w + ni*16 + ln;
      float bias = bf2f(O2b[col]);
      #pragma unroll
      for (int r=0;r<4;r++){
        int rowg = base + mi*16 + hi*4 + r;
        if (rowg < AA){
          float v = acco[mi][ni][r] + bias;
          if (isf32) __builtin_nontemporal_store(v, (float*)out_v + (size_t)rowg*256 + col);
          else       __builtin_nontemporal_store(f2bf(v), (ushort_t*)out_v + (size_t)rowg*256 + col);
        }
      }
    }
}

// ---------------- launch ----------------------------------------------------
extern "C" void kernel_launch(void* const* d_in, const int* in_sizes, int n_in,
                              void* d_out, int out_size, void* d_ws, size_t ws_size,
                              hipStream_t stream) {
  const int* fnode = (const int*)d_in[13];
  const int* fsrc  = (const int*)d_in[14];
  const int* fbond = (const int*)d_in[15];
  const int* agraph = (const int*)d_in[16];
  const int* bgraph = (const int*)d_in[17];
  // depth is fixed at 4 by the problem setup

  k_detect<<<1, 256, 0, stream>>>((const ushort_t*)d_in[0]);
  k_convert<<<(W_TOTAL + 255)/256, 256, 0, stream>>>(
      d_in[0], d_in[1], d_in[2], d_in[3], d_in[4], d_in[5], d_in[6],
      d_in[7], d_in[8], d_in[9], d_in[10], d_in[11], d_in[12]);
  k_tables<<<3*NC + NATOM, 256, 0, stream>>>();
  k_cidx<<<(MM + 255)/256, 256, 0, stream>>>(fnode, fsrc, fbond);
  k_iter0<<<MM/64, 256, 0, stream>>>();                 // h0,uh0 -> buf0
  k_fused<<<MM/32, 256, 0, stream>>>(bgraph, 0, 0);     // it1: buf0 -> buf1
  k_fused<<<MM/32, 256, 0, stream>>>(bgraph, 1, 0);     // it2: buf1 -> buf0
  k_fused<<<MM/32, 256, 0, stream>>>(bgraph, 0, 1);     // it3: buf0 -> buf1 (no uh)
  k_tail<<<(AA + 63)/64, 256, 0, stream>>>(agraph, fnode, (void*)d_out, 1);
}

// Round 5
// 2562.402 us; speedup vs baseline: 1.0226x; 1.0226x over previous
//
#include <hip/hip_runtime.h>

#define MM 200000      // messages
#define AA 100000      // atoms
#define KA 6
#define KB 5
#define NATOM 120
#define NBOND 4
#define NC (NATOM*NBOND)   // 480 combos
#define HH 256
#define HU_LD 512          // interleaved row: [0..255]=h, [256..511]=uh

typedef unsigned short ushort_t;
typedef __attribute__((ext_vector_type(8))) short bf16x8;
typedef __attribute__((ext_vector_type(4))) float f32x4;
typedef __attribute__((ext_vector_type(4))) unsigned int u32x4;

// canonical bf16 weight arena offsets (ushort elements)
#define OFF_Ea   0
#define OFF_Eb   30720
#define OFF_Wz   31744
#define OFF_Wzb  228352
#define OFF_Wr   228608
#define OFF_Ur   359680
#define OFF_Urb  425216
#define OFF_Wh   425472
#define OFF_Whb  622080
#define OFF_O1   622336
#define OFF_O1b  753408
#define OFF_O2   753664
#define OFF_O2b  819200
#define W_TOTAL  819456

// ---------------- static device state ----------------
__device__ ushort_t g_hu0[MM*HU_LD];  // ping
__device__ ushort_t g_hu1[MM*HU_LD];  // pong
__device__ float    g_tr[NC*HH];      // x@Wr^T + Ur_b   per combo
__device__ float    g_tz[NC*HH];      // x-part of z preact + Wz_b
__device__ float    g_th[NC*HH];      // x-part of h preact + Wh_b
__device__ float    g_to1[NATOM*HH];  // hnode-part of O1 preact + O1_b
__device__ int      g_cidx[MM];
__device__ ushort_t c_w[W_TOTAL];     // canonical bf16 weights
__device__ int      g_isf32;          // 1 if float inputs are f32

// ---------------- helpers ----------------
__device__ inline float bf2f(ushort_t u){ return __uint_as_float(((unsigned)u)<<16); }
__device__ inline ushort_t f2bf(float f){
  unsigned u = __float_as_uint(f);
  unsigned r = (u + 0x7FFFu + ((u>>16)&1u)) >> 16;
  return (ushort_t)r;
}
__device__ inline float sigm(float x){ return 1.0f/(1.0f + __expf(-x)); }
__device__ inline float tanh_f(float x){
  float ax = fabsf(x);
  float e = __expf(-2.0f*ax);
  float t = (1.0f - e)/(1.0f + e);
  return copysignf(t, x);
}
// LDS swizzle: ushort-index within a [rows][256] bf16 tile (XOR bits 3..5 by row&7)
__device__ inline int sidx(int row, int col){ return row*256 + (col ^ ((row&7)<<3)); }

__device__ inline bf16x8 ldsA(const ushort_t* tile, int m0, int lane, int k0){
  int row = m0 + (lane & 15);
  int col = k0 + 8*(lane>>4);
  return *(const bf16x8*)(tile + sidx(row, col));
}
__device__ inline bf16x8 ldgB(const ushort_t* W, int ldw, int koff, int n0, int lane, int k0){
  int n = n0 + (lane & 15);
  int k = koff + k0 + 8*(lane>>4);
  return *(const bf16x8*)(W + n*ldw + k);
}
__device__ inline f32x4 mfma16(bf16x8 a, bf16x8 b, f32x4 c){
  return __builtin_amdgcn_mfma_f32_16x16x32_bf16(a, b, c, 0, 0, 0);
}
__device__ inline void st16(ushort_t* p, const ushort_t* lds_src){
  *(u32x4*)p = *(const u32x4*)lds_src;   // plain store: L2 write-back combines
}

// ---------------- K-detect: is the float data f32 or bf16? ------------------
__global__ __launch_bounds__(256) void k_detect(const ushort_t* Ea_raw){
  __shared__ int sbad;
  if (threadIdx.x == 0) sbad = 0;
  __syncthreads();
  float v = bf2f(Ea_raw[2*threadIdx.x]);
  float av = fabsf(v);
  int bad = (av > 1e4f) || (av != 0.0f && av < 1e-30f);
  atomicAdd(&sbad, bad);
  __syncthreads();
  if (threadIdx.x == 0) g_isf32 = (sbad > 64) ? 1 : 0;
}

// ---------------- K-convert: build canonical bf16 arena ---------------------
__global__ __launch_bounds__(256) void k_convert(
    const void* Ea, const void* Eb, const void* Wz, const void* Wzb,
    const void* Wr, const void* Ur, const void* Urb, const void* Wh,
    const void* Whb, const void* O1, const void* O1b, const void* O2,
    const void* O2b)
{
  int idx = blockIdx.x*256 + threadIdx.x;
  if (idx >= W_TOTAL) return;
  const void* src; int j;
  if      (idx < OFF_Eb)  { src = Ea;  j = idx - OFF_Ea; }
  else if (idx < OFF_Wz)  { src = Eb;  j = idx - OFF_Eb; }
  else if (idx < OFF_Wzb) { src = Wz;  j = idx - OFF_Wz; }
  else if (idx < OFF_Wr)  { src = Wzb; j = idx - OFF_Wzb; }
  else if (idx < OFF_Ur)  { src = Wr;  j = idx - OFF_Wr; }
  else if (idx < OFF_Urb) { src = Ur;  j = idx - OFF_Ur; }
  else if (idx < OFF_Wh)  { src = Urb; j = idx - OFF_Urb; }
  else if (idx < OFF_Whb) { src = Wh;  j = idx - OFF_Wh; }
  else if (idx < OFF_O1)  { src = Whb; j = idx - OFF_Whb; }
  else if (idx < OFF_O1b) { src = O1;  j = idx - OFF_O1; }
  else if (idx < OFF_O2)  { src = O1b; j = idx - OFF_O1b; }
  else if (idx < OFF_O2b) { src = O2;  j = idx - OFF_O2; }
  else                    { src = O2b; j = idx - OFF_O2b; }
  ushort_t v;
  if (g_isf32) v = f2bf(((const float*)src)[j]);
  else         v = ((const ushort_t*)src)[j];
  c_w[idx] = v;
}

// ---------------- K0: build tables -----------------------------------------
__global__ __launch_bounds__(256) void k_tables()
{
  const ushort_t* Ea  = c_w + OFF_Ea;
  const ushort_t* Eb  = c_w + OFF_Eb;
  int b = blockIdx.x, o = threadIdx.x;
  if (b < 3*NC) {
    int t = b / NC, c = b % NC, a = c >> 2, bd = c & 3;
    const ushort_t* W; const ushort_t* bias; int ldw;
    if (t == 0)      { W = c_w + OFF_Wr; bias = c_w + OFF_Urb; ldw = 512; }
    else if (t == 1) { W = c_w + OFF_Wz; bias = c_w + OFF_Wzb; ldw = 768; }
    else             { W = c_w + OFF_Wh; bias = c_w + OFF_Whb; ldw = 768; }
    float acc = bf2f(bias[o]);
    const ushort_t* wrow = W + o*ldw;
    for (int d = 0; d < 256; d++) acc += bf2f(Ea[a*256+d]) * bf2f(wrow[d]);
    for (int d = 0; d < 256; d++) acc += bf2f(Eb[bd*256+d]) * bf2f(wrow[256+d]);
    float* T = (t==0) ? g_tr : (t==1) ? g_tz : g_th;
    T[c*256 + o] = acc;
  } else {
    int a = b - 3*NC;
    float acc = bf2f(c_w[OFF_O1b + o]);
    const ushort_t* wrow = c_w + OFF_O1 + o*512;
    for (int d = 0; d < 256; d++) acc += bf2f(Ea[a*256+d]) * bf2f(wrow[d]);
    g_to1[a*256 + o] = acc;
  }
}

// ---------------- K1: combo index per message ------------------------------
__global__ __launch_bounds__(256) void k_cidx(const int* fnode, const int* fsrc, const int* fbond){
  int m = blockIdx.x*256 + threadIdx.x;
  if (m >= MM) return;
  g_cidx[m] = fnode[fsrc[m]]*4 + fbond[m];
}

// ---------------- K2: iteration 0 (h=0 -> table only) + Uh GEMM ------------
__global__ __launch_bounds__(256) void k_iter0(){
  __shared__ __align__(16) ushort_t sT[64*256];
  const ushort_t* Ur = c_w + OFF_Ur;
  ushort_t* hu = g_hu0;
  int base = blockIdx.x * 64;
  int t = threadIdx.x;
  {
    int row = t >> 2, cb = (t & 3) * 64;
    int m = base + row;
    int c = g_cidx[m];
    float msk = (m != 0) ? 1.0f : 0.0f;
    #pragma unroll
    for (int e = 0; e < 64; e += 4){
      int col = cb + e;
      float4 tz = *(const float4*)(g_tz + c*256 + col);
      float4 th = *(const float4*)(g_th + c*256 + col);
      ushort_t h0 = f2bf(msk * sigm(tz.x) * tanh_f(th.x));
      ushort_t h1 = f2bf(msk * sigm(tz.y) * tanh_f(th.y));
      ushort_t h2 = f2bf(msk * sigm(tz.z) * tanh_f(th.z));
      ushort_t h3 = f2bf(msk * sigm(tz.w) * tanh_f(th.w));
      ushort4 hv = make_ushort4(h0,h1,h2,h3);
      *(ushort4*)(hu + (size_t)m*HU_LD + col) = hv;
      *(ushort4*)(sT + sidx(row, col)) = hv;
    }
  }
  __syncthreads();
  int w = t >> 6, lane = t & 63, n0w = w*64, ln = lane & 15, hi = lane >> 4;
  f32x4 acc[4][4];
  #pragma unroll
  for (int i=0;i<4;i++)
    #pragma unroll
    for (int j=0;j<4;j++) acc[i][j] = (f32x4){0.f,0.f,0.f,0.f};
  for (int kt = 0; kt < 8; kt++){
    int k0 = kt*32;
    bf16x8 aF[4], bF[4];
    #pragma unroll
    for (int i=0;i<4;i++) aF[i] = ldsA(sT, i*16, lane, k0);
    #pragma unroll
    for (int i=0;i<4;i++) bF[i] = ldgB(Ur, 256, 0, n0w + i*16, lane, k0);
    #pragma unroll
    for (int mi=0;mi<4;mi++)
      #pragma unroll
      for (int ni=0;ni<4;ni++) acc[mi][ni] = mfma16(aF[mi], bF[ni], acc[mi][ni]);
  }
  __syncthreads();  // done reading sT; reuse for uh staging
  #pragma unroll
  for (int mi=0;mi<4;mi++)
    #pragma unroll
    for (int ni=0;ni<4;ni++){
      int col = n0w + ni*16 + ln;
      #pragma unroll
      for (int r=0;r<4;r++){
        int rowl = mi*16 + hi*4 + r;
        sT[sidx(rowl, col)] = f2bf(acc[mi][ni][r]);
      }
    }
  __syncthreads();
  {
    // coalesced write of uh: 64*256 ushorts, 256 thr x 16B x 8 iters
    #pragma unroll
    for (int it = 0; it < 8; it++){
      int flat = it*2048 + t*8;
      int row = flat >> 8, col = flat & 255;
      st16(hu + (size_t)(base+row)*HU_LD + 256 + col, sT + sidx(row, col));
    }
  }
}

// ---------------- K-fused: gather + GRU update + Uh GEMM (ping-pong) -------
// 16-row tiles (16.4 KB LDS) -> 8 blocks/CU resident for gather-latency hiding
__global__ __launch_bounds__(256) void k_fused(const int* __restrict__ bgraph, int rd, int last){
  __shared__ __align__(16) ushort_t sA[16*256];  // sum_h -> uh_new staging
  __shared__ __align__(16) ushort_t sB[16*256];  // sum_gated -> h_new
  __shared__ int sC[16];
  const ushort_t* __restrict__ hup = rd ? g_hu1 : g_hu0;
  ushort_t* hun = rd ? g_hu0 : g_hu1;
  const ushort_t* Wz = c_w + OFF_Wz;
  const ushort_t* Wh = c_w + OFF_Wh;
  const ushort_t* Ur = c_w + OFF_Ur;
  int base = blockIdx.x*16, t = threadIdx.x;
  int w = t>>6, lane = t&63;

  // ---- gather phase: 4 rows per wave, each lane covers 4 cols ----
  #pragma unroll
  for (int i = 0; i < 4; i++){
    int row = w*4 + i;
    int m = base + row;
    int c = g_cidx[m];
    if (lane == 0) sC[row] = c;
    float4 tr = *(const float4*)(g_tr + c*256 + lane*4);
    int js[KB];
    #pragma unroll
    for (int k = 0; k < KB; k++) js[k] = bgraph[m*KB + k];
    // issue all 10 row loads before consuming (max outstanding loads)
    ushort4 hvv[KB], uvv[KB];
    #pragma unroll
    for (int k = 0; k < KB; k++){
      const ushort_t* rp = hup + (size_t)js[k]*HU_LD;
      hvv[k] = *(const ushort4*)(rp + lane*4);
      uvv[k] = *(const ushort4*)(rp + 256 + lane*4);
    }
    float sh0=0,sh1=0,sh2=0,sh3=0, sg0=0,sg1=0,sg2=0,sg3=0;
    #pragma unroll
    for (int k = 0; k < KB; k++){
      float h0=bf2f(hvv[k].x), h1=bf2f(hvv[k].y), h2=bf2f(hvv[k].z), h3=bf2f(hvv[k].w);
      float r0=sigm(tr.x+bf2f(uvv[k].x)), r1=sigm(tr.y+bf2f(uvv[k].y));
      float r2=sigm(tr.z+bf2f(uvv[k].z)), r3=sigm(tr.w+bf2f(uvv[k].w));
      sh0+=h0; sh1+=h1; sh2+=h2; sh3+=h3;
      sg0+=r0*h0; sg1+=r1*h1; sg2+=r2*h2; sg3+=r3*h3;
    }
    *(ushort4*)(sA + sidx(row, lane*4)) = make_ushort4(f2bf(sh0),f2bf(sh1),f2bf(sh2),f2bf(sh3));
    *(ushort4*)(sB + sidx(row, lane*4)) = make_ushort4(f2bf(sg0),f2bf(sg1),f2bf(sg2),f2bf(sg3));
  }
  __syncthreads();

  // ---- GEMM phase: z (sA x Wz) and pre_h (sB x Wh), M=16 ----
  int n0w = w*64, ln = lane&15, hi = lane>>4;
  f32x4 accz[4], acch[4];
  #pragma unroll
  for (int j=0;j<4;j++){ accz[j]=(f32x4){0,0,0,0}; acch[j]=(f32x4){0,0,0,0}; }
  for (int kt = 0; kt < 8; kt++){
    int k0 = kt*32;
    bf16x8 aZ = ldsA(sA, 0, lane, k0);
    bf16x8 aH = ldsA(sB, 0, lane, k0);
    #pragma unroll
    for (int i=0;i<4;i++){
      bf16x8 bZ = ldgB(Wz, 768, 512, n0w + i*16, lane, k0);
      accz[i] = mfma16(aZ, bZ, accz[i]);
    }
    #pragma unroll
    for (int i=0;i<4;i++){
      bf16x8 bH = ldgB(Wh, 768, 512, n0w + i*16, lane, k0);
      acch[i] = mfma16(aH, bH, acch[i]);
    }
  }
  __syncthreads();   // all waves done reading sA/sB

  // ---- epilogue: GRU update into sB (LDS only) ----
  #pragma unroll
  for (int ni=0;ni<4;ni++){
    int col = n0w + ni*16 + ln;
    #pragma unroll
    for (int r=0;r<4;r++){
      int rowl = hi*4 + r;
      int rowg = base + rowl;
      int c = sC[rowl];
      float shv = bf2f(sA[sidx(rowl, col)]);
      float z  = sigm(g_tz[c*256+col] + accz[ni][r]);
      float ph = tanh_f(g_th[c*256+col] + acch[ni][r]);
      float hn = (1.0f - z)*shv + z*ph;
      if (rowg == 0) hn = 0.f;
      sB[sidx(rowl,col)] = f2bf(hn);
    }
  }
  __syncthreads();   // sB = h_new visible; sA free

  if (!last){
    // ---- Uh GEMM: h_new x Ur^T, stage into sA ----
    f32x4 accu[4];
    #pragma unroll
    for (int j=0;j<4;j++) accu[j]=(f32x4){0,0,0,0};
    for (int kt = 0; kt < 8; kt++){
      int k0 = kt*32;
      bf16x8 aU = ldsA(sB, 0, lane, k0);
      #pragma unroll
      for (int i=0;i<4;i++){
        bf16x8 bU = ldgB(Ur, 256, 0, n0w + i*16, lane, k0);
        accu[i] = mfma16(aU, bU, accu[i]);
      }
    }
    #pragma unroll
    for (int ni=0;ni<4;ni++){
      int col = n0w + ni*16 + ln;
      #pragma unroll
      for (int r=0;r<4;r++){
        int rowl = hi*4 + r;
        sA[sidx(rowl, col)] = f2bf(accu[ni][r]);
      }
    }
    __syncthreads();
  }

  // ---- coalesced write phase: h (sB) always, uh (sA) if !last ----
  {
    // 16 rows x 256 cols = 4096 ushorts per half; 256 thr x 8 ushorts x 2 iters
    #pragma unroll
    for (int it = 0; it < 2; it++){
      int flat = it*2048 + t*8;
      int row = flat >> 8, col = flat & 255;
      size_t rb = (size_t)(base+row)*HU_LD;
      st16(hun + rb + col, sB + sidx(row, col));
      if (!last) st16(hun + rb + 256 + col, sA + sidx(row, col));
    }
  }
}

// ---------------- K5: tail (agraph gather + O1 relu + O2) ------------------
__global__ __launch_bounds__(256) void k_tail(const int* agraph, const int* fnode,
                                              void* out_v, int rd){
  __shared__ __align__(16) ushort_t sT[64*256];
  const ushort_t* __restrict__ hup = rd ? g_hu1 : g_hu0;
  const ushort_t* O1  = c_w + OFF_O1;
  const ushort_t* O2  = c_w + OFF_O2;
  const ushort_t* O2b = c_w + OFF_O2b;
  int base = blockIdx.x*64, t = threadIdx.x;
  int w = t>>6, lane = t&63;
  for (int i = 0; i < 16; i++){
    int rowl = w*16 + i;
    int a = base + rowl;
    float a0=0,a1=0,a2=0,a3=0;
    if (a < AA){
      int js[KA];
      #pragma unroll
      for (int k = 0; k < KA; k++) js[k] = agraph[a*KA + k];
      ushort4 hvv[KA];
      #pragma unroll
      for (int k = 0; k < KA; k++)
        hvv[k] = *(const ushort4*)(hup + (size_t)js[k]*HU_LD + lane*4);
      #pragma unroll
      for (int k = 0; k < KA; k++){
        a0+=bf2f(hvv[k].x); a1+=bf2f(hvv[k].y); a2+=bf2f(hvv[k].z); a3+=bf2f(hvv[k].w);
      }
    }
    *(ushort4*)(sT + sidx(rowl, lane*4)) = make_ushort4(f2bf(a0),f2bf(a1),f2bf(a2),f2bf(a3));
  }
  __syncthreads();
  int n0w = w*64, ln = lane&15, hi = lane>>4;
  f32x4 acc[4][4];
  #pragma unroll
  for (int i=0;i<4;i++)
    #pragma unroll
    for (int j=0;j<4;j++) acc[i][j]=(f32x4){0,0,0,0};
  for (int kt = 0; kt < 8; kt++){
    int k0 = kt*32;
    bf16x8 aF[4], bF[4];
    #pragma unroll
    for (int i=0;i<4;i++) aF[i] = ldsA(sT, i*16, lane, k0);
    #pragma unroll
    for (int i=0;i<4;i++) bF[i] = ldgB(O1, 512, 256, n0w + i*16, lane, k0);
    #pragma unroll
    for (int mi=0;mi<4;mi++)
      #pragma unroll
      for (int ni=0;ni<4;ni++) acc[mi][ni] = mfma16(aF[mi], bF[ni], acc[mi][ni]);
  }
  __syncthreads();
  #pragma unroll
  for (int mi=0;mi<4;mi++)
    #pragma unroll
    for (int ni=0;ni<4;ni++){
      int col = n0w + ni*16 + ln;
      #pragma unroll
      for (int r=0;r<4;r++){
        int rowl = mi*16 + hi*4 + r;
        int a = base + rowl;
        int tt = (a < AA) ? fnode[a] : 0;
        float pre = g_to1[tt*256+col] + acc[mi][ni][r];
        sT[sidx(rowl,col)] = f2bf(fmaxf(pre, 0.f));
      }
    }
  __syncthreads();
  f32x4 acco[4][4];
  #pragma unroll
  for (int i=0;i<4;i++)
    #pragma unroll
    for (int j=0;j<4;j++) acco[i][j]=(f32x4){0,0,0,0};
  for (int kt = 0; kt < 8; kt++){
    int k0 = kt*32;
    bf16x8 aF[4], bF[4];
    #pragma unroll
    for (int i=0;i<4;i++) aF[i] = ldsA(sT, i*16, lane, k0);
    #pragma unroll
    for (int i=0;i<4;i++) bF[i] = ldgB(O2, 256, 0, n0w + i*16, lane, k0);
    #pragma unroll
    for (int mi=0;mi<4;mi++)
      #pragma unroll
      for (int ni=0;ni<4;ni++) acco[mi][ni] = mfma16(aF[mi], bF[ni], acco[mi][ni]);
  }
  int isf32 = g_isf32;
  #pragma unroll
  for (int mi=0;mi<4;mi++)
    #pragma unroll
    for (int ni=0;ni<4;ni++){
      int col = n0w + ni*16 + ln;
      float bias = bf2f(O2b[col]);
      #pragma unroll
      for (int r=0;r<4;r++){
        int rowg = base + mi*16 + hi*4 + r;
        if (rowg < AA){
          float v = acco[mi][ni][r] + bias;
          if (isf32) ((float*)out_v)[(size_t)rowg*256 + col] = v;
          else       ((ushort_t*)out_v)[(size_t)rowg*256 + col] = f2bf(v);
        }
      }
    }
}

// ---------------- launch ----------------------------------------------------
extern "C" void kernel_launch(void* const* d_in, const int* in_sizes, int n_in,
                              void* d_out, int out_size, void* d_ws, size_t ws_size,
                              hipStream_t stream) {
  const int* fnode = (const int*)d_in[13];
  const int* fsrc  = (const int*)d_in[14];
  const int* fbond = (const int*)d_in[15];
  const int* agraph = (const int*)d_in[16];
  const int* bgraph = (const int*)d_in[17];
  // depth is fixed at 4 by the problem setup

  k_detect<<<1, 256, 0, stream>>>((const ushort_t*)d_in[0]);
  k_convert<<<(W_TOTAL + 255)/256, 256, 0, stream>>>(
      d_in[0], d_in[1], d_in[2], d_in[3], d_in[4], d_in[5], d_in[6],
      d_in[7], d_in[8], d_in[9], d_in[10], d_in[11], d_in[12]);
  k_tables<<<3*NC + NATOM, 256, 0, stream>>>();
  k_cidx<<<(MM + 255)/256, 256, 0, stream>>>(fnode, fsrc, fbond);
  k_iter0<<<MM/64, 256, 0, stream>>>();                 // h0,uh0 -> buf0
  k_fused<<<MM/16, 256, 0, stream>>>(bgraph, 0, 0);     // it1: buf0 -> buf1
  k_fused<<<MM/16, 256, 0, stream>>>(bgraph, 1, 0);     // it2: buf1 -> buf0
  k_fused<<<MM/16, 256, 0, stream>>>(bgraph, 0, 1);     // it3: buf0 -> buf1 (no uh)
  k_tail<<<(AA + 63)/64, 256, 0, stream>>>(agraph, fnode, (void*)d_out, 1);
}

// Round 6
// 1783.102 us; speedup vs baseline: 1.4696x; 1.4370x over previous
//
#include <hip/hip_runtime.h>

#define MM 200000      // messages
#define AA 100000      // atoms
#define KA 6
#define KB 5
#define NATOM 120
#define NBOND 4
#define NC (NATOM*NBOND)   // 480 combos
#define HH 256
#define HU_LD 512          // interleaved row: [0..255]=h, [256..511]=uh

typedef unsigned short ushort_t;
typedef __attribute__((ext_vector_type(8))) short bf16x8;
typedef __attribute__((ext_vector_type(4))) float f32x4;
typedef __attribute__((ext_vector_type(4))) unsigned int u32x4;

// canonical bf16 weight arena offsets (ushort elements)
#define OFF_Ea   0
#define OFF_Eb   30720
#define OFF_Wz   31744
#define OFF_Wzb  228352
#define OFF_Wr   228608
#define OFF_Ur   359680
#define OFF_Urb  425216
#define OFF_Wh   425472
#define OFF_Whb  622080
#define OFF_O1   622336
#define OFF_O1b  753408
#define OFF_O2   753664
#define OFF_O2b  819200
#define W_TOTAL  819456

// ---------------- static device state ----------------
__device__ ushort_t g_hu0[MM*HU_LD];  // ping
__device__ ushort_t g_hu1[MM*HU_LD];  // pong
__device__ float    g_tr[NC*HH];      // x@Wr^T + Ur_b   per combo
__device__ float    g_tz[NC*HH];      // x-part of z preact + Wz_b
__device__ float    g_th[NC*HH];      // x-part of h preact + Wh_b
__device__ float    g_to1[NATOM*HH];  // hnode-part of O1 preact + O1_b
__device__ int      g_cidx[MM];
__device__ ushort_t c_w[W_TOTAL];     // canonical bf16 weights
__device__ int      g_isf32;          // 1 if float inputs are f32

// ---------------- helpers ----------------
__device__ inline float bf2f(ushort_t u){ return __uint_as_float(((unsigned)u)<<16); }
__device__ inline ushort_t f2bf(float f){
  unsigned u = __float_as_uint(f);
  unsigned r = (u + 0x7FFFu + ((u>>16)&1u)) >> 16;
  return (ushort_t)r;
}
__device__ inline float sigm(float x){ return 1.0f/(1.0f + __expf(-x)); }
__device__ inline float tanh_f(float x){
  float ax = fabsf(x);
  float e = __expf(-2.0f*ax);
  float t = (1.0f - e)/(1.0f + e);
  return copysignf(t, x);
}
// LDS swizzle: ushort-index within a [rows][256] bf16 tile (XOR bits 3..5 by row&7)
__device__ inline int sidx(int row, int col){ return row*256 + (col ^ ((row&7)<<3)); }

__device__ inline bf16x8 ldsA(const ushort_t* tile, int m0, int lane, int k0){
  int row = m0 + (lane & 15);
  int col = k0 + 8*(lane>>4);
  return *(const bf16x8*)(tile + sidx(row, col));
}
__device__ inline bf16x8 ldgB(const ushort_t* W, int ldw, int koff, int n0, int lane, int k0){
  int n = n0 + (lane & 15);
  int k = koff + k0 + 8*(lane>>4);
  return *(const bf16x8*)(W + n*ldw + k);
}
__device__ inline f32x4 mfma16(bf16x8 a, bf16x8 b, f32x4 c){
  return __builtin_amdgcn_mfma_f32_16x16x32_bf16(a, b, c, 0, 0, 0);
}
__device__ inline void st16(ushort_t* p, const ushort_t* lds_src){
  *(u32x4*)p = *(const u32x4*)lds_src;   // plain store: L2 write-back combines
}

// ---------------- K-detect: is the float data f32 or bf16? ------------------
__global__ __launch_bounds__(256) void k_detect(const ushort_t* Ea_raw){
  __shared__ int sbad;
  if (threadIdx.x == 0) sbad = 0;
  __syncthreads();
  float v = bf2f(Ea_raw[2*threadIdx.x]);
  float av = fabsf(v);
  int bad = (av > 1e4f) || (av != 0.0f && av < 1e-30f);
  atomicAdd(&sbad, bad);
  __syncthreads();
  if (threadIdx.x == 0) g_isf32 = (sbad > 64) ? 1 : 0;
}

// ---------------- K-convert: build canonical bf16 arena ---------------------
__global__ __launch_bounds__(256) void k_convert(
    const void* Ea, const void* Eb, const void* Wz, const void* Wzb,
    const void* Wr, const void* Ur, const void* Urb, const void* Wh,
    const void* Whb, const void* O1, const void* O1b, const void* O2,
    const void* O2b)
{
  int idx = blockIdx.x*256 + threadIdx.x;
  if (idx >= W_TOTAL) return;
  const void* src; int j;
  if      (idx < OFF_Eb)  { src = Ea;  j = idx - OFF_Ea; }
  else if (idx < OFF_Wz)  { src = Eb;  j = idx - OFF_Eb; }
  else if (idx < OFF_Wzb) { src = Wz;  j = idx - OFF_Wz; }
  else if (idx < OFF_Wr)  { src = Wzb; j = idx - OFF_Wzb; }
  else if (idx < OFF_Ur)  { src = Wr;  j = idx - OFF_Wr; }
  else if (idx < OFF_Urb) { src = Ur;  j = idx - OFF_Ur; }
  else if (idx < OFF_Wh)  { src = Urb; j = idx - OFF_Urb; }
  else if (idx < OFF_Whb) { src = Wh;  j = idx - OFF_Wh; }
  else if (idx < OFF_O1)  { src = Whb; j = idx - OFF_Whb; }
  else if (idx < OFF_O1b) { src = O1;  j = idx - OFF_O1; }
  else if (idx < OFF_O2)  { src = O1b; j = idx - OFF_O1b; }
  else if (idx < OFF_O2b) { src = O2;  j = idx - OFF_O2; }
  else                    { src = O2b; j = idx - OFF_O2b; }
  ushort_t v;
  if (g_isf32) v = f2bf(((const float*)src)[j]);
  else         v = ((const ushort_t*)src)[j];
  c_w[idx] = v;
}

// ---------------- K0: build tables -----------------------------------------
__global__ __launch_bounds__(256) void k_tables()
{
  const ushort_t* Ea  = c_w + OFF_Ea;
  const ushort_t* Eb  = c_w + OFF_Eb;
  int b = blockIdx.x, o = threadIdx.x;
  if (b < 3*NC) {
    int t = b / NC, c = b % NC, a = c >> 2, bd = c & 3;
    const ushort_t* W; const ushort_t* bias; int ldw;
    if (t == 0)      { W = c_w + OFF_Wr; bias = c_w + OFF_Urb; ldw = 512; }
    else if (t == 1) { W = c_w + OFF_Wz; bias = c_w + OFF_Wzb; ldw = 768; }
    else             { W = c_w + OFF_Wh; bias = c_w + OFF_Whb; ldw = 768; }
    float acc = bf2f(bias[o]);
    const ushort_t* wrow = W + o*ldw;
    for (int d = 0; d < 256; d++) acc += bf2f(Ea[a*256+d]) * bf2f(wrow[d]);
    for (int d = 0; d < 256; d++) acc += bf2f(Eb[bd*256+d]) * bf2f(wrow[256+d]);
    float* T = (t==0) ? g_tr : (t==1) ? g_tz : g_th;
    T[c*256 + o] = acc;
  } else {
    int a = b - 3*NC;
    float acc = bf2f(c_w[OFF_O1b + o]);
    const ushort_t* wrow = c_w + OFF_O1 + o*512;
    for (int d = 0; d < 256; d++) acc += bf2f(Ea[a*256+d]) * bf2f(wrow[d]);
    g_to1[a*256 + o] = acc;
  }
}

// ---------------- K1: combo index per message ------------------------------
__global__ __launch_bounds__(256) void k_cidx(const int* fnode, const int* fsrc, const int* fbond){
  int m = blockIdx.x*256 + threadIdx.x;
  if (m >= MM) return;
  g_cidx[m] = fnode[fsrc[m]]*4 + fbond[m];
}

// ---------------- K2: iteration 0 (h=0 -> table only) + Uh GEMM ------------
__global__ __launch_bounds__(256) void k_iter0(){
  __shared__ __align__(16) ushort_t sT[64*256];
  const ushort_t* Ur = c_w + OFF_Ur;
  ushort_t* hu = g_hu0;
  int base = blockIdx.x * 64;
  int t = threadIdx.x;
  {
    int row = t >> 2, cb = (t & 3) * 64;
    int m = base + row;
    int c = g_cidx[m];
    float msk = (m != 0) ? 1.0f : 0.0f;
    #pragma unroll
    for (int e = 0; e < 64; e += 4){
      int col = cb + e;
      float4 tz = *(const float4*)(g_tz + c*256 + col);
      float4 th = *(const float4*)(g_th + c*256 + col);
      ushort_t h0 = f2bf(msk * sigm(tz.x) * tanh_f(th.x));
      ushort_t h1 = f2bf(msk * sigm(tz.y) * tanh_f(th.y));
      ushort_t h2 = f2bf(msk * sigm(tz.z) * tanh_f(th.z));
      ushort_t h3 = f2bf(msk * sigm(tz.w) * tanh_f(th.w));
      ushort4 hv = make_ushort4(h0,h1,h2,h3);
      *(ushort4*)(hu + (size_t)m*HU_LD + col) = hv;
      *(ushort4*)(sT + sidx(row, col)) = hv;
    }
  }
  __syncthreads();
  int w = t >> 6, lane = t & 63, n0w = w*64, ln = lane & 15, hi = lane >> 4;
  f32x4 acc[4][4];
  #pragma unroll
  for (int i=0;i<4;i++)
    #pragma unroll
    for (int j=0;j<4;j++) acc[i][j] = (f32x4){0.f,0.f,0.f,0.f};
  for (int kt = 0; kt < 8; kt++){
    int k0 = kt*32;
    bf16x8 aF[4], bF[4];
    #pragma unroll
    for (int i=0;i<4;i++) aF[i] = ldsA(sT, i*16, lane, k0);
    #pragma unroll
    for (int i=0;i<4;i++) bF[i] = ldgB(Ur, 256, 0, n0w + i*16, lane, k0);
    #pragma unroll
    for (int mi=0;mi<4;mi++)
      #pragma unroll
      for (int ni=0;ni<4;ni++) acc[mi][ni] = mfma16(aF[mi], bF[ni], acc[mi][ni]);
  }
  __syncthreads();  // done reading sT; reuse for uh staging
  #pragma unroll
  for (int mi=0;mi<4;mi++)
    #pragma unroll
    for (int ni=0;ni<4;ni++){
      int col = n0w + ni*16 + ln;
      #pragma unroll
      for (int r=0;r<4;r++){
        int rowl = mi*16 + hi*4 + r;
        sT[sidx(rowl, col)] = f2bf(acc[mi][ni][r]);
      }
    }
  __syncthreads();
  {
    // coalesced write of uh: 64*256 ushorts, 256 thr x 16B x 8 iters
    #pragma unroll
    for (int it = 0; it < 8; it++){
      int flat = it*2048 + t*8;
      int row = flat >> 8, col = flat & 255;
      st16(hu + (size_t)(base+row)*HU_LD + 256 + col, sT + sidx(row, col));
    }
  }
}

// ---------------- K-fused: gather + GRU update + Uh GEMM (ping-pong) -------
// 32-row tiles, software-pipelined gather (stage row i+1 loads during row i VALU)
__global__ __launch_bounds__(256,3) void k_fused(const int* __restrict__ bgraph, int rd, int last){
  __shared__ __align__(16) ushort_t sA[32*256];  // sum_h -> uh_new staging
  __shared__ __align__(16) ushort_t sB[32*256];  // sum_gated -> h_new
  __shared__ int sC[32];
  __shared__ int sJ[32*KB];
  const ushort_t* __restrict__ hup = rd ? g_hu1 : g_hu0;
  ushort_t* hun = rd ? g_hu0 : g_hu1;
  const ushort_t* Wz = c_w + OFF_Wz;
  const ushort_t* Wh = c_w + OFF_Wh;
  const ushort_t* Ur = c_w + OFF_Ur;
  int base = blockIdx.x*32, t = threadIdx.x;
  int w = t>>6, lane = t&63;

  // ---- header: tile's combo indices + bgraph slice into LDS (coalesced) ----
  if (t < 32)  sC[t] = g_cidx[base + t];
  if (t < 32*KB) sJ[t] = bgraph[base*KB + t];
  __syncthreads();

  // ---- pipelined gather: 8 rows/wave, double-buffered staged loads ----
  auto issue = [&](int i, ushort4 (&hv)[KB], ushort4 (&uv)[KB], float4& tr){
    int row = w*8 + i;
    tr = *(const float4*)(g_tr + sC[row]*256 + lane*4);
    #pragma unroll
    for (int k = 0; k < KB; k++){
      const ushort_t* rp = hup + (size_t)sJ[row*KB + k]*HU_LD;
      hv[k] = *(const ushort4*)(rp + lane*4);
      uv[k] = *(const ushort4*)(rp + 256 + lane*4);
    }
  };
  auto process = [&](int i, ushort4 (&hv)[KB], ushort4 (&uv)[KB], float4& tr){
    int row = w*8 + i;
    float sh0=0,sh1=0,sh2=0,sh3=0, sg0=0,sg1=0,sg2=0,sg3=0;
    #pragma unroll
    for (int k = 0; k < KB; k++){
      float h0=bf2f(hv[k].x), h1=bf2f(hv[k].y), h2=bf2f(hv[k].z), h3=bf2f(hv[k].w);
      sg0 += sigm(tr.x+bf2f(uv[k].x))*h0;
      sg1 += sigm(tr.y+bf2f(uv[k].y))*h1;
      sg2 += sigm(tr.z+bf2f(uv[k].z))*h2;
      sg3 += sigm(tr.w+bf2f(uv[k].w))*h3;
      sh0+=h0; sh1+=h1; sh2+=h2; sh3+=h3;
    }
    *(ushort4*)(sA + sidx(row, lane*4)) = make_ushort4(f2bf(sh0),f2bf(sh1),f2bf(sh2),f2bf(sh3));
    *(ushort4*)(sB + sidx(row, lane*4)) = make_ushort4(f2bf(sg0),f2bf(sg1),f2bf(sg2),f2bf(sg3));
  };
  {
    ushort4 h0[KB], u0[KB], h1[KB], u1[KB];
    float4 t0, t1;
    issue(0, h0, u0, t0);
    issue(1, h1, u1, t1);
    process(0, h0, u0, t0);
    issue(2, h0, u0, t0);
    process(1, h1, u1, t1);
    issue(3, h1, u1, t1);
    process(2, h0, u0, t0);
    issue(4, h0, u0, t0);
    process(3, h1, u1, t1);
    issue(5, h1, u1, t1);
    process(4, h0, u0, t0);
    issue(6, h0, u0, t0);
    process(5, h1, u1, t1);
    issue(7, h1, u1, t1);
    process(6, h0, u0, t0);
    process(7, h1, u1, t1);
  }
  __syncthreads();

  // ---- GEMM phase: z (sA x Wz) and pre_h (sB x Wh), M=32 ----
  int n0w = w*64, ln = lane&15, hi = lane>>4;
  f32x4 accz[2][4], acch[2][4];
  #pragma unroll
  for (int i=0;i<2;i++)
    #pragma unroll
    for (int j=0;j<4;j++){ accz[i][j]=(f32x4){0,0,0,0}; acch[i][j]=(f32x4){0,0,0,0}; }
  for (int kt = 0; kt < 8; kt++){
    int k0 = kt*32;
    bf16x8 aF[2], bF[4];
    aF[0] = ldsA(sA, 0, lane, k0);
    aF[1] = ldsA(sA, 16, lane, k0);
    #pragma unroll
    for (int i=0;i<4;i++) bF[i] = ldgB(Wz, 768, 512, n0w + i*16, lane, k0);
    #pragma unroll
    for (int mi=0;mi<2;mi++)
      #pragma unroll
      for (int ni=0;ni<4;ni++) accz[mi][ni] = mfma16(aF[mi], bF[ni], accz[mi][ni]);
  }
  for (int kt = 0; kt < 8; kt++){
    int k0 = kt*32;
    bf16x8 aF[2], bF[4];
    aF[0] = ldsA(sB, 0, lane, k0);
    aF[1] = ldsA(sB, 16, lane, k0);
    #pragma unroll
    for (int i=0;i<4;i++) bF[i] = ldgB(Wh, 768, 512, n0w + i*16, lane, k0);
    #pragma unroll
    for (int mi=0;mi<2;mi++)
      #pragma unroll
      for (int ni=0;ni<4;ni++) acch[mi][ni] = mfma16(aF[mi], bF[ni], acch[mi][ni]);
  }
  __syncthreads();   // all waves done reading sA/sB

  // ---- epilogue: GRU update into sB (LDS only) ----
  #pragma unroll
  for (int mi=0;mi<2;mi++)
    #pragma unroll
    for (int ni=0;ni<4;ni++){
      int col = n0w + ni*16 + ln;
      #pragma unroll
      for (int r=0;r<4;r++){
        int rowl = mi*16 + hi*4 + r;
        int rowg = base + rowl;
        int c = sC[rowl];
        float shv = bf2f(sA[sidx(rowl, col)]);
        float z  = sigm(g_tz[c*256+col] + accz[mi][ni][r]);
        float ph = tanh_f(g_th[c*256+col] + acch[mi][ni][r]);
        float hn = (1.0f - z)*shv + z*ph;
        if (rowg == 0) hn = 0.f;
        sB[sidx(rowl,col)] = f2bf(hn);
      }
    }
  __syncthreads();   // sB = h_new visible; sA free

  if (!last){
    // ---- Uh GEMM: h_new x Ur^T, stage into sA ----
    f32x4 accu[2][4];
    #pragma unroll
    for (int i=0;i<2;i++)
      #pragma unroll
      for (int j=0;j<4;j++) accu[i][j]=(f32x4){0,0,0,0};
    for (int kt = 0; kt < 8; kt++){
      int k0 = kt*32;
      bf16x8 aF[2], bF[4];
      aF[0] = ldsA(sB, 0, lane, k0);
      aF[1] = ldsA(sB, 16, lane, k0);
      #pragma unroll
      for (int i=0;i<4;i++) bF[i] = ldgB(Ur, 256, 0, n0w + i*16, lane, k0);
      #pragma unroll
      for (int mi=0;mi<2;mi++)
        #pragma unroll
        for (int ni=0;ni<4;ni++) accu[mi][ni] = mfma16(aF[mi], bF[ni], accu[mi][ni]);
    }
    #pragma unroll
    for (int mi=0;mi<2;mi++)
      #pragma unroll
      for (int ni=0;ni<4;ni++){
        int col = n0w + ni*16 + ln;
        #pragma unroll
        for (int r=0;r<4;r++){
          int rowl = mi*16 + hi*4 + r;
          sA[sidx(rowl, col)] = f2bf(accu[mi][ni][r]);
        }
      }
    __syncthreads();
  }

  // ---- coalesced write phase: h (sB) always, uh (sA) if !last ----
  {
    // 32 rows x 256 cols = 8192 ushorts per half; 256 thr x 8 ushorts x 4 iters
    #pragma unroll
    for (int it = 0; it < 4; it++){
      int flat = it*2048 + t*8;
      int row = flat >> 8, col = flat & 255;
      size_t rb = (size_t)(base+row)*HU_LD;
      st16(hun + rb + col, sB + sidx(row, col));
      if (!last) st16(hun + rb + 256 + col, sA + sidx(row, col));
    }
  }
}

// ---------------- K5: tail (agraph gather + O1 relu + O2) ------------------
__global__ __launch_bounds__(256) void k_tail(const int* agraph, const int* fnode,
                                              void* out_v, int rd){
  __shared__ __align__(16) ushort_t sT[64*256];
  const ushort_t* __restrict__ hup = rd ? g_hu1 : g_hu0;
  const ushort_t* O1  = c_w + OFF_O1;
  const ushort_t* O2  = c_w + OFF_O2;
  const ushort_t* O2b = c_w + OFF_O2b;
  int base = blockIdx.x*64, t = threadIdx.x;
  int w = t>>6, lane = t&63;
  for (int i = 0; i < 16; i++){
    int rowl = w*16 + i;
    int a = base + rowl;
    float a0=0,a1=0,a2=0,a3=0;
    if (a < AA){
      int js[KA];
      #pragma unroll
      for (int k = 0; k < KA; k++) js[k] = agraph[a*KA + k];
      ushort4 hvv[KA];
      #pragma unroll
      for (int k = 0; k < KA; k++)
        hvv[k] = *(const ushort4*)(hup + (size_t)js[k]*HU_LD + lane*4);
      #pragma unroll
      for (int k = 0; k < KA; k++){
        a0+=bf2f(hvv[k].x); a1+=bf2f(hvv[k].y); a2+=bf2f(hvv[k].z); a3+=bf2f(hvv[k].w);
      }
    }
    *(ushort4*)(sT + sidx(rowl, lane*4)) = make_ushort4(f2bf(a0),f2bf(a1),f2bf(a2),f2bf(a3));
  }
  __syncthreads();
  int n0w = w*64, ln = lane&15, hi = lane>>4;
  f32x4 acc[4][4];
  #pragma unroll
  for (int i=0;i<4;i++)
    #pragma unroll
    for (int j=0;j<4;j++) acc[i][j]=(f32x4){0,0,0,0};
  for (int kt = 0; kt < 8; kt++){
    int k0 = kt*32;
    bf16x8 aF[4], bF[4];
    #pragma unroll
    for (int i=0;i<4;i++) aF[i] = ldsA(sT, i*16, lane, k0);
    #pragma unroll
    for (int i=0;i<4;i++) bF[i] = ldgB(O1, 512, 256, n0w + i*16, lane, k0);
    #pragma unroll
    for (int mi=0;mi<4;mi++)
      #pragma unroll
      for (int ni=0;ni<4;ni++) acc[mi][ni] = mfma16(aF[mi], bF[ni], acc[mi][ni]);
  }
  __syncthreads();
  #pragma unroll
  for (int mi=0;mi<4;mi++)
    #pragma unroll
    for (int ni=0;ni<4;ni++){
      int col = n0w + ni*16 + ln;
      #pragma unroll
      for (int r=0;r<4;r++){
        int rowl = mi*16 + hi*4 + r;
        int a = base + rowl;
        int tt = (a < AA) ? fnode[a] : 0;
        float pre = g_to1[tt*256+col] + acc[mi][ni][r];
        sT[sidx(rowl,col)] = f2bf(fmaxf(pre, 0.f));
      }
    }
  __syncthreads();
  f32x4 acco[4][4];
  #pragma unroll
  for (int i=0;i<4;i++)
    #pragma unroll
    for (int j=0;j<4;j++) acco[i][j]=(f32x4){0,0,0,0};
  for (int kt = 0; kt < 8; kt++){
    int k0 = kt*32;
    bf16x8 aF[4], bF[4];
    #pragma unroll
    for (int i=0;i<4;i++) aF[i] = ldsA(sT, i*16, lane, k0);
    #pragma unroll
    for (int i=0;i<4;i++) bF[i] = ldgB(O2, 256, 0, n0w + i*16, lane, k0);
    #pragma unroll
    for (int mi=0;mi<4;mi++)
      #pragma unroll
      for (int ni=0;ni<4;ni++) acco[mi][ni] = mfma16(aF[mi], bF[ni], acco[mi][ni]);
  }
  int isf32 = g_isf32;
  #pragma unroll
  for (int mi=0;mi<4;mi++)
    #pragma unroll
    for (int ni=0;ni<4;ni++){
      int col = n0w + ni*16 + ln;
      float bias = bf2f(O2b[col]);
      #pragma unroll
      for (int r=0;r<4;r++){
        int rowg = base + mi*16 + hi*4 + r;
        if (rowg < AA){
          float v = acco[mi][ni][r] + bias;
          if (isf32) ((float*)out_v)[(size_t)rowg*256 + col] = v;
          else       ((ushort_t*)out_v)[(size_t)rowg*256 + col] = f2bf(v);
        }
      }
    }
}

// ---------------- launch ----------------------------------------------------
extern "C" void kernel_launch(void* const* d_in, const int* in_sizes, int n_in,
                              void* d_out, int out_size, void* d_ws, size_t ws_size,
                              hipStream_t stream) {
  const int* fnode = (const int*)d_in[13];
  const int* fsrc  = (const int*)d_in[14];
  const int* fbond = (const int*)d_in[15];
  const int* agraph = (const int*)d_in[16];
  const int* bgraph = (const int*)d_in[17];
  // depth is fixed at 4 by the problem setup

  k_detect<<<1, 256, 0, stream>>>((const ushort_t*)d_in[0]);
  k_convert<<<(W_TOTAL + 255)/256, 256, 0, stream>>>(
      d_in[0], d_in[1], d_in[2], d_in[3], d_in[4], d_in[5], d_in[6],
      d_in[7], d_in[8], d_in[9], d_in[10], d_in[11], d_in[12]);
  k_tables<<<3*NC + NATOM, 256, 0, stream>>>();
  k_cidx<<<(MM + 255)/256, 256, 0, stream>>>(fnode, fsrc, fbond);
  k_iter0<<<MM/64, 256, 0, stream>>>();                 // h0,uh0 -> buf0
  k_fused<<<MM/32, 256, 0, stream>>>(bgraph, 0, 0);     // it1: buf0 -> buf1
  k_fused<<<MM/32, 256, 0, stream>>>(bgraph, 1, 0);     // it2: buf1 -> buf0
  k_fused<<<MM/32, 256, 0, stream>>>(bgraph, 0, 1);     // it3: buf0 -> buf1 (no uh)
  k_tail<<<(AA + 63)/64, 256, 0, stream>>>(agraph, fnode, (void*)d_out, 1);
}

// Round 7
// 1708.712 us; speedup vs baseline: 1.5335x; 1.0435x over previous
//
#include <hip/hip_runtime.h>

#define MM 200000      // messages
#define AA 100000      // atoms
#define KA 6
#define KB 5
#define NATOM 120
#define NBOND 4
#define NC (NATOM*NBOND)   // 480 combos
#define HH 256
#define HU_LD 512          // interleaved row: [0..255]=h, [256..511]=uh

typedef unsigned short ushort_t;
typedef __attribute__((ext_vector_type(8))) short bf16x8;
typedef __attribute__((ext_vector_type(8))) unsigned short u16x8;
typedef __attribute__((ext_vector_type(4))) float f32x4;
typedef __attribute__((ext_vector_type(4))) unsigned int u32x4;

// canonical bf16 weight arena offsets (ushort elements)
#define OFF_Ea   0
#define OFF_Eb   30720
#define OFF_Wz   31744
#define OFF_Wzb  228352
#define OFF_Wr   228608
#define OFF_Ur   359680
#define OFF_Urb  425216
#define OFF_Wh   425472
#define OFF_Whb  622080
#define OFF_O1   622336
#define OFF_O1b  753408
#define OFF_O2   753664
#define OFF_O2b  819200
#define W_TOTAL  819456

// ---------------- static device state ----------------
__device__ ushort_t g_hu0[MM*HU_LD];  // ping
__device__ ushort_t g_hu1[MM*HU_LD];  // pong
__device__ ushort_t g_trb[NC*HH];     // bf16: x@Wr^T + Ur_b per combo
__device__ float    g_tz[NC*HH];      // x-part of z preact + Wz_b
__device__ float    g_th[NC*HH];      // x-part of h preact + Wh_b
__device__ float    g_to1[NATOM*HH];  // hnode-part of O1 preact + O1_b
__device__ int      g_cidx[MM];
__device__ ushort_t c_w[W_TOTAL];     // canonical bf16 weights
__device__ int      g_isf32;          // 1 if float inputs are f32

// ---------------- helpers ----------------
__device__ inline float bf2f(ushort_t u){ return __uint_as_float(((unsigned)u)<<16); }
__device__ inline ushort_t f2bf(float f){
  unsigned u = __float_as_uint(f);
  unsigned r = (u + 0x7FFFu + ((u>>16)&1u)) >> 16;
  return (ushort_t)r;
}
__device__ inline float sigm(float x){ return 1.0f/(1.0f + __expf(-x)); }
__device__ inline float tanh_f(float x){
  float ax = fabsf(x);
  float e = __expf(-2.0f*ax);
  float t = (1.0f - e)/(1.0f + e);
  return copysignf(t, x);
}
// LDS swizzle: ushort-index within a [rows][256] bf16 tile (XOR bits 3..5 by row&7)
__device__ inline int sidx(int row, int col){ return row*256 + (col ^ ((row&7)<<3)); }

__device__ inline bf16x8 ldsA(const ushort_t* tile, int m0, int lane, int k0){
  int row = m0 + (lane & 15);
  int col = k0 + 8*(lane>>4);
  return *(const bf16x8*)(tile + sidx(row, col));
}
__device__ inline bf16x8 ldgB(const ushort_t* W, int ldw, int koff, int n0, int lane, int k0){
  int n = n0 + (lane & 15);
  int k = koff + k0 + 8*(lane>>4);
  return *(const bf16x8*)(W + n*ldw + k);
}
__device__ inline f32x4 mfma16(bf16x8 a, bf16x8 b, f32x4 c){
  return __builtin_amdgcn_mfma_f32_16x16x32_bf16(a, b, c, 0, 0, 0);
}
__device__ inline void st16(ushort_t* p, const ushort_t* lds_src){
  *(u32x4*)p = *(const u32x4*)lds_src;   // plain store: L2 write-back combines
}

// ---------------- K-detect: is the float data f32 or bf16? ------------------
__global__ __launch_bounds__(256) void k_detect(const ushort_t* Ea_raw){
  __shared__ int sbad;
  if (threadIdx.x == 0) sbad = 0;
  __syncthreads();
  float v = bf2f(Ea_raw[2*threadIdx.x]);
  float av = fabsf(v);
  int bad = (av > 1e4f) || (av != 0.0f && av < 1e-30f);
  atomicAdd(&sbad, bad);
  __syncthreads();
  if (threadIdx.x == 0) g_isf32 = (sbad > 64) ? 1 : 0;
}

// ---------------- K-convert: build canonical bf16 arena ---------------------
__global__ __launch_bounds__(256) void k_convert(
    const void* Ea, const void* Eb, const void* Wz, const void* Wzb,
    const void* Wr, const void* Ur, const void* Urb, const void* Wh,
    const void* Whb, const void* O1, const void* O1b, const void* O2,
    const void* O2b)
{
  int idx = blockIdx.x*256 + threadIdx.x;
  if (idx >= W_TOTAL) return;
  const void* src; int j;
  if      (idx < OFF_Eb)  { src = Ea;  j = idx - OFF_Ea; }
  else if (idx < OFF_Wz)  { src = Eb;  j = idx - OFF_Eb; }
  else if (idx < OFF_Wzb) { src = Wz;  j = idx - OFF_Wz; }
  else if (idx < OFF_Wr)  { src = Wzb; j = idx - OFF_Wzb; }
  else if (idx < OFF_Ur)  { src = Wr;  j = idx - OFF_Wr; }
  else if (idx < OFF_Urb) { src = Ur;  j = idx - OFF_Ur; }
  else if (idx < OFF_Wh)  { src = Urb; j = idx - OFF_Urb; }
  else if (idx < OFF_Whb) { src = Wh;  j = idx - OFF_Wh; }
  else if (idx < OFF_O1)  { src = Whb; j = idx - OFF_Whb; }
  else if (idx < OFF_O1b) { src = O1;  j = idx - OFF_O1; }
  else if (idx < OFF_O2)  { src = O1b; j = idx - OFF_O1b; }
  else if (idx < OFF_O2b) { src = O2;  j = idx - OFF_O2; }
  else                    { src = O2b; j = idx - OFF_O2b; }
  ushort_t v;
  if (g_isf32) v = f2bf(((const float*)src)[j]);
  else         v = ((const ushort_t*)src)[j];
  c_w[idx] = v;
}

// ---------------- K0: build tables -----------------------------------------
__global__ __launch_bounds__(256) void k_tables()
{
  const ushort_t* Ea  = c_w + OFF_Ea;
  const ushort_t* Eb  = c_w + OFF_Eb;
  int b = blockIdx.x, o = threadIdx.x;
  if (b < 3*NC) {
    int t = b / NC, c = b % NC, a = c >> 2, bd = c & 3;
    const ushort_t* W; const ushort_t* bias; int ldw;
    if (t == 0)      { W = c_w + OFF_Wr; bias = c_w + OFF_Urb; ldw = 512; }
    else if (t == 1) { W = c_w + OFF_Wz; bias = c_w + OFF_Wzb; ldw = 768; }
    else             { W = c_w + OFF_Wh; bias = c_w + OFF_Whb; ldw = 768; }
    float acc = bf2f(bias[o]);
    const ushort_t* wrow = W + o*ldw;
    for (int d = 0; d < 256; d++) acc += bf2f(Ea[a*256+d]) * bf2f(wrow[d]);
    for (int d = 0; d < 256; d++) acc += bf2f(Eb[bd*256+d]) * bf2f(wrow[256+d]);
    if (t == 0)      g_trb[c*256 + o] = f2bf(acc);
    else if (t == 1) g_tz[c*256 + o] = acc;
    else             g_th[c*256 + o] = acc;
  } else {
    int a = b - 3*NC;
    float acc = bf2f(c_w[OFF_O1b + o]);
    const ushort_t* wrow = c_w + OFF_O1 + o*512;
    for (int d = 0; d < 256; d++) acc += bf2f(Ea[a*256+d]) * bf2f(wrow[d]);
    g_to1[a*256 + o] = acc;
  }
}

// ---------------- K1: combo index per message ------------------------------
__global__ __launch_bounds__(256) void k_cidx(const int* fnode, const int* fsrc, const int* fbond){
  int m = blockIdx.x*256 + threadIdx.x;
  if (m >= MM) return;
  g_cidx[m] = fnode[fsrc[m]]*4 + fbond[m];
}

// ---------------- K2: iteration 0 (h=0 -> table only) + Uh GEMM ------------
__global__ __launch_bounds__(256) void k_iter0(){
  __shared__ __align__(16) ushort_t sT[64*256];
  const ushort_t* Ur = c_w + OFF_Ur;
  ushort_t* hu = g_hu0;
  int base = blockIdx.x * 64;
  int t = threadIdx.x;
  {
    int row = t >> 2, cb = (t & 3) * 64;
    int m = base + row;
    int c = g_cidx[m];
    float msk = (m != 0) ? 1.0f : 0.0f;
    #pragma unroll
    for (int e = 0; e < 64; e += 4){
      int col = cb + e;
      float4 tz = *(const float4*)(g_tz + c*256 + col);
      float4 th = *(const float4*)(g_th + c*256 + col);
      ushort_t h0 = f2bf(msk * sigm(tz.x) * tanh_f(th.x));
      ushort_t h1 = f2bf(msk * sigm(tz.y) * tanh_f(th.y));
      ushort_t h2 = f2bf(msk * sigm(tz.z) * tanh_f(th.z));
      ushort_t h3 = f2bf(msk * sigm(tz.w) * tanh_f(th.w));
      ushort4 hv = make_ushort4(h0,h1,h2,h3);
      *(ushort4*)(hu + (size_t)m*HU_LD + col) = hv;
      *(ushort4*)(sT + sidx(row, col)) = hv;
    }
  }
  __syncthreads();
  int w = t >> 6, lane = t & 63, n0w = w*64, ln = lane & 15, hi = lane >> 4;
  f32x4 acc[4][4];
  #pragma unroll
  for (int i=0;i<4;i++)
    #pragma unroll
    for (int j=0;j<4;j++) acc[i][j] = (f32x4){0.f,0.f,0.f,0.f};
  for (int kt = 0; kt < 8; kt++){
    int k0 = kt*32;
    bf16x8 aF[4], bF[4];
    #pragma unroll
    for (int i=0;i<4;i++) aF[i] = ldsA(sT, i*16, lane, k0);
    #pragma unroll
    for (int i=0;i<4;i++) bF[i] = ldgB(Ur, 256, 0, n0w + i*16, lane, k0);
    #pragma unroll
    for (int mi=0;mi<4;mi++)
      #pragma unroll
      for (int ni=0;ni<4;ni++) acc[mi][ni] = mfma16(aF[mi], bF[ni], acc[mi][ni]);
  }
  __syncthreads();  // done reading sT; reuse for uh staging
  #pragma unroll
  for (int mi=0;mi<4;mi++)
    #pragma unroll
    for (int ni=0;ni<4;ni++){
      int col = n0w + ni*16 + ln;
      #pragma unroll
      for (int r=0;r<4;r++){
        int rowl = mi*16 + hi*4 + r;
        sT[sidx(rowl, col)] = f2bf(acc[mi][ni][r]);
      }
    }
  __syncthreads();
  {
    // coalesced write of uh: 64*256 ushorts, 256 thr x 16B x 8 iters
    #pragma unroll
    for (int it = 0; it < 8; it++){
      int flat = it*2048 + t*8;
      int row = flat >> 8, col = flat & 255;
      st16(hu + (size_t)(base+row)*HU_LD + 256 + col, sT + sidx(row, col));
    }
  }
}

// ---------------- K-fused: gather + GRU update + Uh GEMM (ping-pong) -------
// 32-row tiles; pair-based 16B gather loads, 2-deep software pipeline
__global__ __launch_bounds__(256,4) void k_fused(const int* __restrict__ bgraph, int rd, int last){
  __shared__ __align__(16) ushort_t sA[32*256];  // sum_h -> uh_new staging
  __shared__ __align__(16) ushort_t sB[32*256];  // sum_gated -> h_new
  __shared__ int sC[32];
  __shared__ int sJ[32*KB];
  const ushort_t* __restrict__ hup = rd ? g_hu1 : g_hu0;
  ushort_t* hun = rd ? g_hu0 : g_hu1;
  const ushort_t* Wz = c_w + OFF_Wz;
  const ushort_t* Wh = c_w + OFF_Wh;
  const ushort_t* Ur = c_w + OFF_Ur;
  int base = blockIdx.x*32, t = threadIdx.x;
  int w = t>>6, lane = t&63;
  int sub = lane & 31, half = lane >> 5;

  // ---- header: tile's combo indices + bgraph slice into LDS (coalesced) ----
  if (t < 32)  sC[t] = g_cidx[base + t];
  if (t < 32*KB) sJ[t] = bgraph[base*KB + t];
  __syncthreads();

  // ---- pipelined gather: 8 rows/wave as 4 pairs; lane covers 8 cols ----
  auto issue = [&](int p, bf16x8 (&hv)[KB], bf16x8 (&uv)[KB], bf16x8& trv){
    int row = w*8 + 2*p + half;
    trv = *(const bf16x8*)(g_trb + sC[row]*256 + sub*8);
    #pragma unroll
    for (int k = 0; k < KB; k++){
      const ushort_t* rp = hup + (size_t)sJ[row*KB + k]*HU_LD + sub*8;
      hv[k] = *(const bf16x8*)(rp);
      uv[k] = *(const bf16x8*)(rp + 256);   // folds to inst offset:512
    }
  };
  auto process = [&](int p, bf16x8 (&hv)[KB], bf16x8 (&uv)[KB], bf16x8& trv){
    int row = w*8 + 2*p + half;
    float tre[8];
    #pragma unroll
    for (int e = 0; e < 8; e++) tre[e] = bf2f((ushort_t)trv[e]);
    float sh[8] = {0,0,0,0,0,0,0,0};
    float sg[8] = {0,0,0,0,0,0,0,0};
    #pragma unroll
    for (int k = 0; k < KB; k++){
      #pragma unroll
      for (int e = 0; e < 8; e++){
        float h = bf2f((ushort_t)hv[k][e]);
        float r = sigm(tre[e] + bf2f((ushort_t)uv[k][e]));
        sh[e] += h;
        sg[e] += r*h;
      }
    }
    u16x8 ph, pg;
    #pragma unroll
    for (int e = 0; e < 8; e++){ ph[e] = f2bf(sh[e]); pg[e] = f2bf(sg[e]); }
    *(u16x8*)(sA + sidx(row, sub*8)) = ph;
    *(u16x8*)(sB + sidx(row, sub*8)) = pg;
  };
  {
    bf16x8 h0[KB], u0[KB], h1[KB], u1[KB];
    bf16x8 t0v, t1v;
    issue(0, h0, u0, t0v);
    issue(1, h1, u1, t1v);
    process(0, h0, u0, t0v);
    issue(2, h0, u0, t0v);
    process(1, h1, u1, t1v);
    issue(3, h1, u1, t1v);
    process(2, h0, u0, t0v);
    process(3, h1, u1, t1v);
  }
  __syncthreads();

  // ---- GEMM phase: z (sA x Wz) and pre_h (sB x Wh), M=32 ----
  int n0w = w*64, ln = lane&15, hi = lane>>4;
  f32x4 accz[2][4], acch[2][4];
  #pragma unroll
  for (int i=0;i<2;i++)
    #pragma unroll
    for (int j=0;j<4;j++){ accz[i][j]=(f32x4){0,0,0,0}; acch[i][j]=(f32x4){0,0,0,0}; }
  for (int kt = 0; kt < 8; kt++){
    int k0 = kt*32;
    bf16x8 aF[2], bF[4];
    aF[0] = ldsA(sA, 0, lane, k0);
    aF[1] = ldsA(sA, 16, lane, k0);
    #pragma unroll
    for (int i=0;i<4;i++) bF[i] = ldgB(Wz, 768, 512, n0w + i*16, lane, k0);
    #pragma unroll
    for (int mi=0;mi<2;mi++)
      #pragma unroll
      for (int ni=0;ni<4;ni++) accz[mi][ni] = mfma16(aF[mi], bF[ni], accz[mi][ni]);
  }
  for (int kt = 0; kt < 8; kt++){
    int k0 = kt*32;
    bf16x8 aF[2], bF[4];
    aF[0] = ldsA(sB, 0, lane, k0);
    aF[1] = ldsA(sB, 16, lane, k0);
    #pragma unroll
    for (int i=0;i<4;i++) bF[i] = ldgB(Wh, 768, 512, n0w + i*16, lane, k0);
    #pragma unroll
    for (int mi=0;mi<2;mi++)
      #pragma unroll
      for (int ni=0;ni<4;ni++) acch[mi][ni] = mfma16(aF[mi], bF[ni], acch[mi][ni]);
  }
  __syncthreads();   // all waves done reading sA/sB

  // ---- epilogue: GRU update into sB (LDS only) ----
  #pragma unroll
  for (int mi=0;mi<2;mi++)
    #pragma unroll
    for (int ni=0;ni<4;ni++){
      int col = n0w + ni*16 + ln;
      #pragma unroll
      for (int r=0;r<4;r++){
        int rowl = mi*16 + hi*4 + r;
        int rowg = base + rowl;
        int c = sC[rowl];
        float shv = bf2f(sA[sidx(rowl, col)]);
        float z  = sigm(g_tz[c*256+col] + accz[mi][ni][r]);
        float ph = tanh_f(g_th[c*256+col] + acch[mi][ni][r]);
        float hn = (1.0f - z)*shv + z*ph;
        if (rowg == 0) hn = 0.f;
        sB[sidx(rowl,col)] = f2bf(hn);
      }
    }
  __syncthreads();   // sB = h_new visible; sA free

  if (!last){
    // ---- Uh GEMM: h_new x Ur^T, stage into sA ----
    f32x4 accu[2][4];
    #pragma unroll
    for (int i=0;i<2;i++)
      #pragma unroll
      for (int j=0;j<4;j++) accu[i][j]=(f32x4){0,0,0,0};
    for (int kt = 0; kt < 8; kt++){
      int k0 = kt*32;
      bf16x8 aF[2], bF[4];
      aF[0] = ldsA(sB, 0, lane, k0);
      aF[1] = ldsA(sB, 16, lane, k0);
      #pragma unroll
      for (int i=0;i<4;i++) bF[i] = ldgB(Ur, 256, 0, n0w + i*16, lane, k0);
      #pragma unroll
      for (int mi=0;mi<2;mi++)
        #pragma unroll
        for (int ni=0;ni<4;ni++) accu[mi][ni] = mfma16(aF[mi], bF[ni], accu[mi][ni]);
    }
    #pragma unroll
    for (int mi=0;mi<2;mi++)
      #pragma unroll
      for (int ni=0;ni<4;ni++){
        int col = n0w + ni*16 + ln;
        #pragma unroll
        for (int r=0;r<4;r++){
          int rowl = mi*16 + hi*4 + r;
          sA[sidx(rowl, col)] = f2bf(accu[mi][ni][r]);
        }
      }
    __syncthreads();
  }

  // ---- coalesced write phase: h (sB) always, uh (sA) if !last ----
  {
    // 32 rows x 256 cols = 8192 ushorts per half; 256 thr x 8 ushorts x 4 iters
    #pragma unroll
    for (int it = 0; it < 4; it++){
      int flat = it*2048 + t*8;
      int row = flat >> 8, col = flat & 255;
      size_t rb = (size_t)(base+row)*HU_LD;
      st16(hun + rb + col, sB + sidx(row, col));
      if (!last) st16(hun + rb + 256 + col, sA + sidx(row, col));
    }
  }
}

// ---------------- K5: tail (agraph gather + O1 relu + O2) ------------------
__global__ __launch_bounds__(256) void k_tail(const int* agraph, const int* fnode,
                                              void* out_v, int rd){
  __shared__ __align__(16) ushort_t sT[64*256];
  const ushort_t* __restrict__ hup = rd ? g_hu1 : g_hu0;
  const ushort_t* O1  = c_w + OFF_O1;
  const ushort_t* O2  = c_w + OFF_O2;
  const ushort_t* O2b = c_w + OFF_O2b;
  int base = blockIdx.x*64, t = threadIdx.x;
  int w = t>>6, lane = t&63;
  int sub = lane & 31, half = lane >> 5;

  // ---- pair-based 16B gather over agraph, 2-deep pipeline ----
  auto tissue = [&](int p, bf16x8 (&hv)[KA]){
    int rowl = w*16 + 2*p + half;
    int a = base + rowl;
    int aa = (a < AA) ? a : 0;
    #pragma unroll
    for (int k = 0; k < KA; k++){
      int j = agraph[aa*KA + k];
      hv[k] = *(const bf16x8*)(hup + (size_t)j*HU_LD + sub*8);
    }
  };
  auto tproc = [&](int p, bf16x8 (&hv)[KA]){
    int rowl = w*16 + 2*p + half;
    float s[8] = {0,0,0,0,0,0,0,0};
    #pragma unroll
    for (int k = 0; k < KA; k++)
      #pragma unroll
      for (int e = 0; e < 8; e++) s[e] += bf2f((ushort_t)hv[k][e]);
    u16x8 pk;
    #pragma unroll
    for (int e = 0; e < 8; e++) pk[e] = f2bf(s[e]);
    *(u16x8*)(sT + sidx(rowl, sub*8)) = pk;
  };
  {
    bf16x8 b0[KA], b1[KA];
    tissue(0, b0); tissue(1, b1);
    tproc(0, b0);  tissue(2, b0);
    tproc(1, b1);  tissue(3, b1);
    tproc(2, b0);  tissue(4, b0);
    tproc(3, b1);  tissue(5, b1);
    tproc(4, b0);  tissue(6, b0);
    tproc(5, b1);  tissue(7, b1);
    tproc(6, b0);
    tproc(7, b1);
  }
  __syncthreads();
  int n0w = w*64, ln = lane&15, hi = lane>>4;
  f32x4 acc[4][4];
  #pragma unroll
  for (int i=0;i<4;i++)
    #pragma unroll
    for (int j=0;j<4;j++) acc[i][j]=(f32x4){0,0,0,0};
  for (int kt = 0; kt < 8; kt++){
    int k0 = kt*32;
    bf16x8 aF[4], bF[4];
    #pragma unroll
    for (int i=0;i<4;i++) aF[i] = ldsA(sT, i*16, lane, k0);
    #pragma unroll
    for (int i=0;i<4;i++) bF[i] = ldgB(O1, 512, 256, n0w + i*16, lane, k0);
    #pragma unroll
    for (int mi=0;mi<4;mi++)
      #pragma unroll
      for (int ni=0;ni<4;ni++) acc[mi][ni] = mfma16(aF[mi], bF[ni], acc[mi][ni]);
  }
  __syncthreads();
  #pragma unroll
  for (int mi=0;mi<4;mi++)
    #pragma unroll
    for (int ni=0;ni<4;ni++){
      int col = n0w + ni*16 + ln;
      #pragma unroll
      for (int r=0;r<4;r++){
        int rowl = mi*16 + hi*4 + r;
        int a = base + rowl;
        int tt = (a < AA) ? fnode[a] : 0;
        float pre = g_to1[tt*256+col] + acc[mi][ni][r];
        sT[sidx(rowl,col)] = f2bf(fmaxf(pre, 0.f));
      }
    }
  __syncthreads();
  f32x4 acco[4][4];
  #pragma unroll
  for (int i=0;i<4;i++)
    #pragma unroll
    for (int j=0;j<4;j++) acco[i][j]=(f32x4){0,0,0,0};
  for (int kt = 0; kt < 8; kt++){
    int k0 = kt*32;
    bf16x8 aF[4], bF[4];
    #pragma unroll
    for (int i=0;i<4;i++) aF[i] = ldsA(sT, i*16, lane, k0);
    #pragma unroll
    for (int i=0;i<4;i++) bF[i] = ldgB(O2, 256, 0, n0w + i*16, lane, k0);
    #pragma unroll
    for (int mi=0;mi<4;mi++)
      #pragma unroll
      for (int ni=0;ni<4;ni++) acco[mi][ni] = mfma16(aF[mi], bF[ni], acco[mi][ni]);
  }
  int isf32 = g_isf32;
  #pragma unroll
  for (int mi=0;mi<4;mi++)
    #pragma unroll
    for (int ni=0;ni<4;ni++){
      int col = n0w + ni*16 + ln;
      float bias = bf2f(O2b[col]);
      #pragma unroll
      for (int r=0;r<4;r++){
        int rowg = base + mi*16 + hi*4 + r;
        if (rowg < AA){
          float v = acco[mi][ni][r] + bias;
          if (isf32) ((float*)out_v)[(size_t)rowg*256 + col] = v;
          else       ((ushort_t*)out_v)[(size_t)rowg*256 + col] = f2bf(v);
        }
      }
    }
}

// ---------------- launch ----------------------------------------------------
extern "C" void kernel_launch(void* const* d_in, const int* in_sizes, int n_in,
                              void* d_out, int out_size, void* d_ws, size_t ws_size,
                              hipStream_t stream) {
  const int* fnode = (const int*)d_in[13];
  const int* fsrc  = (const int*)d_in[14];
  const int* fbond = (const int*)d_in[15];
  const int* agraph = (const int*)d_in[16];
  const int* bgraph = (const int*)d_in[17];
  // depth is fixed at 4 by the problem setup

  k_detect<<<1, 256, 0, stream>>>((const ushort_t*)d_in[0]);
  k_convert<<<(W_TOTAL + 255)/256, 256, 0, stream>>>(
      d_in[0], d_in[1], d_in[2], d_in[3], d_in[4], d_in[5], d_in[6],
      d_in[7], d_in[8], d_in[9], d_in[10], d_in[11], d_in[12]);
  k_tables<<<3*NC + NATOM, 256, 0, stream>>>();
  k_cidx<<<(MM + 255)/256, 256, 0, stream>>>(fnode, fsrc, fbond);
  k_iter0<<<MM/64, 256, 0, stream>>>();                 // h0,uh0 -> buf0
  k_fused<<<MM/32, 256, 0, stream>>>(bgraph, 0, 0);     // it1: buf0 -> buf1
  k_fused<<<MM/32, 256, 0, stream>>>(bgraph, 1, 0);     // it2: buf1 -> buf0
  k_fused<<<MM/32, 256, 0, stream>>>(bgraph, 0, 1);     // it3: buf0 -> buf1 (no uh)
  k_tail<<<(AA + 63)/64, 256, 0, stream>>>(agraph, fnode, (void*)d_out, 1);
}